// Round 1
// baseline (502.456 us; speedup 1.0000x reference)
//
#include <hip/hip_runtime.h>

// Problem constants (fixed by the reference)
#define Bn  4
#define Cn  128
#define CQn 64
#define Nn  4096   // H*W = 64*64

// ws layout (floats):
//  Q: [B][N][CQ]  offset 0        size 1048576  (4 MB)
//  K: [B][CQ][N]  offset 1048576  size 1048576  (4 MB)
//  V: [B][C][N]   offset 2097152  size 2097152  (8 MB)

// ---------------------------------------------------------------------------
// Kernel 1: fused QKV 1x1-conv projection.
// Per batch: Y[256][N] = W[256][128] * X[128][N] + bias, tiled 64x64.
// gridDim = (N/64, 4 o-tiles, B). o-tile 0 -> Q, 1 -> K, 2/3 -> V halves.
// ---------------------------------------------------------------------------
__global__ __launch_bounds__(256) void qkv_proj(
    const float* __restrict__ x,
    const float* __restrict__ Wq, const float* __restrict__ bq,
    const float* __restrict__ Wk, const float* __restrict__ bk,
    const float* __restrict__ Wv, const float* __restrict__ bv,
    float* __restrict__ Q, float* __restrict__ K, float* __restrict__ V)
{
    const int ntile = blockIdx.x;
    const int otile = blockIdx.y;
    const int b     = blockIdx.z;
    const int tid   = threadIdx.x;
    const int nbase = ntile * 64;

    __shared__ float Ws[64][132];   // [o][c], c contiguous, +4 pad (16B aligned rows)
    __shared__ float Xs[128][68];   // [c][n], n contiguous, +4 pad

    const float* Wsrc; const float* bsrc; int obase;
    if (otile == 0)      { Wsrc = Wq;                     bsrc = bq;      obase = 0; }
    else if (otile == 1) { Wsrc = Wk;                     bsrc = bk;      obase = 0; }
    else                 { Wsrc = Wv + (otile - 2) * 64 * Cn;
                           bsrc = bv + (otile - 2) * 64;  obase = (otile - 2) * 64; }

    // Load W tile: 64 x 128 floats = 2048 float4
    for (int u = 0; u < 8; ++u) {
        int f = tid + u * 256;
        int row = f >> 5;
        int col = (f & 31) * 4;
        *(float4*)&Ws[row][col] = *(const float4*)&Wsrc[row * Cn + col];
    }
    // Load X tile: [128 c][64 n] = 2048 float4
    const float* xb = x + ((size_t)b * Cn) * Nn + nbase;
    for (int u = 0; u < 8; ++u) {
        int f = tid + u * 256;
        int c = f >> 4;
        int n = (f & 15) * 4;
        *(float4*)&Xs[c][n] = *(const float4*)&xb[(size_t)c * Nn + n];
    }
    __syncthreads();

    const int o0 = (tid >> 4) * 4;
    const int n0 = (tid & 15) * 4;
    float acc[4][4] = {};

    for (int c = 0; c < Cn; c += 4) {
        float4 w4[4], x4[4];
        for (int oo = 0; oo < 4; ++oo) w4[oo] = *(const float4*)&Ws[o0 + oo][c];
        for (int cc = 0; cc < 4; ++cc) x4[cc] = *(const float4*)&Xs[c + cc][n0];
        for (int oo = 0; oo < 4; ++oo) {
            const float* wv = (const float*)&w4[oo];
            for (int cc = 0; cc < 4; ++cc) {
                const float ws = wv[cc];
                const float* xp = (const float*)&x4[cc];
                acc[oo][0] += ws * xp[0];
                acc[oo][1] += ws * xp[1];
                acc[oo][2] += ws * xp[2];
                acc[oo][3] += ws * xp[3];
            }
        }
    }

    float bias[4];
    for (int oo = 0; oo < 4; ++oo) bias[oo] = bsrc[o0 + oo];

    if (otile == 0) {
        // Q layout [B][N][CQ]: float4 over o
        for (int nn = 0; nn < 4; ++nn) {
            float4 o4 = make_float4(acc[0][nn] + bias[0], acc[1][nn] + bias[1],
                                    acc[2][nn] + bias[2], acc[3][nn] + bias[3]);
            *(float4*)&Q[((size_t)b * Nn + nbase + n0 + nn) * CQn + o0] = o4;
        }
    } else if (otile == 1) {
        // K layout [B][CQ][N]: float4 over n
        for (int oo = 0; oo < 4; ++oo) {
            float4 o4 = make_float4(acc[oo][0] + bias[oo], acc[oo][1] + bias[oo],
                                    acc[oo][2] + bias[oo], acc[oo][3] + bias[oo]);
            *(float4*)&K[((size_t)b * CQn + o0 + oo) * Nn + nbase + n0] = o4;
        }
    } else {
        // V layout [B][C][N]
        const int og = obase + o0;
        for (int oo = 0; oo < 4; ++oo) {
            float4 o4 = make_float4(acc[oo][0] + bias[oo], acc[oo][1] + bias[oo],
                                    acc[oo][2] + bias[oo], acc[oo][3] + bias[oo]);
            *(float4*)&V[((size_t)b * Cn + og + oo) * Nn + nbase + n0] = o4;
        }
    }
}

// ---------------------------------------------------------------------------
// Kernel 2: flash-style attention. One block per (b, 64-query i-tile).
// 256 threads. Streams 64 j-tiles of 64 keys with online softmax.
// ---------------------------------------------------------------------------
__global__ __launch_bounds__(256) void attn(
    const float* __restrict__ Q,   // [B][N][CQ]
    const float* __restrict__ K,   // [B][CQ][N]
    const float* __restrict__ V,   // [B][C][N]
    float* __restrict__ out)       // [B][C][N]
{
    const int itile = blockIdx.x;
    const int b     = blockIdx.y;
    const int tid   = threadIdx.x;
    const int ibase = itile * 64;

    __shared__ float Qs[64][68];    // [i][c]
    __shared__ float Ks[64][68];    // [c][j]
    __shared__ float Vs[128][68];   // [c][j]
    __shared__ float Ps[64][68];    // [i][j] scores -> probs
    __shared__ float m_s[64], l_s[64], alpha_s[64];

    // Load Q tile (persistent): 64 x 64 = 1024 float4
    const float* qb = Q + ((size_t)b * Nn + ibase) * CQn;
    for (int u = 0; u < 4; ++u) {
        int f = tid + u * 256;
        int i = f >> 4;
        int c = (f & 15) * 4;
        *(float4*)&Qs[i][c] = *(const float4*)&qb[(size_t)i * CQn + c];
    }
    if (tid < 64) { m_s[tid] = -3.402823466e38f; l_s[tid] = 0.f; }

    const int i0 = (tid >> 4) * 4;   // 4 query rows per thread
    const int j0 = (tid & 15) * 4;   // 4 key cols per thread (scores phase)
    const int c0 = (tid & 15);       // PV: channels c0 + 16*cc

    float oacc[4][8] = {};           // [ii][cc] accumulators

    const float* kb = K + (size_t)b * CQn * Nn;
    const float* vb = V + (size_t)b * Cn  * Nn;

    for (int jt = 0; jt < 64; ++jt) {
        const int jbase = jt * 64;
        __syncthreads();   // (A) prev PV / Q-load complete before overwriting tiles

        // Load K tile [64 c][64 j] = 1024 float4
        for (int u = 0; u < 4; ++u) {
            int f = tid + u * 256;
            int c = f >> 4;
            int j = (f & 15) * 4;
            *(float4*)&Ks[c][j] = *(const float4*)&kb[(size_t)c * Nn + jbase + j];
        }
        // Load V tile [128 c][64 j] = 2048 float4
        for (int u = 0; u < 8; ++u) {
            int f = tid + u * 256;
            int c = f >> 4;
            int j = (f & 15) * 4;
            *(float4*)&Vs[c][j] = *(const float4*)&vb[(size_t)c * Nn + jbase + j];
        }
        __syncthreads();   // (B)

        // Scores: s[4i][4j] = Q[i][:] . K[:][j]
        float s[4][4] = {};
        for (int c = 0; c < CQn; c += 4) {
            float4 q4[4], k4[4];
            for (int ii = 0; ii < 4; ++ii) q4[ii] = *(const float4*)&Qs[i0 + ii][c];
            for (int cc = 0; cc < 4; ++cc) k4[cc] = *(const float4*)&Ks[c + cc][j0];
            for (int ii = 0; ii < 4; ++ii) {
                const float* qv = (const float*)&q4[ii];
                for (int cc = 0; cc < 4; ++cc) {
                    const float qs = qv[cc];
                    const float* kp = (const float*)&k4[cc];
                    s[ii][0] += qs * kp[0];
                    s[ii][1] += qs * kp[1];
                    s[ii][2] += qs * kp[2];
                    s[ii][3] += qs * kp[3];
                }
            }
        }
        for (int ii = 0; ii < 4; ++ii)
            *(float4*)&Ps[i0 + ii][j0] = make_float4(s[ii][0], s[ii][1], s[ii][2], s[ii][3]);
        __syncthreads();   // (C)

        // Online softmax: 4 threads per row
        {
            const int r = tid >> 2, part = tid & 3;
            float tm = -3.402823466e38f;
            for (int e = 0; e < 16; ++e) tm = fmaxf(tm, Ps[r][part * 16 + e]);
            tm = fmaxf(tm, __shfl_xor(tm, 1));
            tm = fmaxf(tm, __shfl_xor(tm, 2));
            const float mold = m_s[r];
            const float mnew = fmaxf(mold, tm);
            float ts = 0.f;
            for (int e = 0; e < 16; ++e) {
                float p = __expf(Ps[r][part * 16 + e] - mnew);
                Ps[r][part * 16 + e] = p;
                ts += p;
            }
            ts += __shfl_xor(ts, 1);
            ts += __shfl_xor(ts, 2);
            if (part == 0) {
                const float alpha = __expf(mold - mnew);   // 0 on first tile
                l_s[r] = l_s[r] * alpha + ts;
                m_s[r] = mnew;
                alpha_s[r] = alpha;
            }
        }
        __syncthreads();   // (D)

        // PV: oacc[ii][cc] = alpha*oacc + sum_j P[i][j] * V[c][j]
        float al[4];
        for (int ii = 0; ii < 4; ++ii) al[ii] = alpha_s[i0 + ii];
        for (int ii = 0; ii < 4; ++ii)
            for (int cc = 0; cc < 8; ++cc) oacc[ii][cc] *= al[ii];

        for (int j = 0; j < 64; j += 4) {
            float4 p4[4], v4[8];
            for (int ii = 0; ii < 4; ++ii) p4[ii] = *(const float4*)&Ps[i0 + ii][j];
            for (int cc = 0; cc < 8; ++cc) v4[cc] = *(const float4*)&Vs[c0 + cc * 16][j];
            for (int ii = 0; ii < 4; ++ii) {
                const float* pp = (const float*)&p4[ii];
                for (int cc = 0; cc < 8; ++cc) {
                    const float* vv = (const float*)&v4[cc];
                    oacc[ii][cc] += pp[0] * vv[0] + pp[1] * vv[1]
                                  + pp[2] * vv[2] + pp[3] * vv[3];
                }
            }
        }
    }

    // Epilogue: out[b][c][i] = oacc / l
    float linv[4];
    for (int ii = 0; ii < 4; ++ii) linv[ii] = 1.f / l_s[i0 + ii];
    float* ob = out + (size_t)b * Cn * Nn;
    for (int cc = 0; cc < 8; ++cc) {
        const int c = c0 + cc * 16;
        float4 o4 = make_float4(oacc[0][cc] * linv[0], oacc[1][cc] * linv[1],
                                oacc[2][cc] * linv[2], oacc[3][cc] * linv[3]);
        *(float4*)&ob[(size_t)c * Nn + ibase + i0] = o4;
    }
}

extern "C" void kernel_launch(void* const* d_in, const int* in_sizes, int n_in,
                              void* d_out, int out_size, void* d_ws, size_t ws_size,
                              hipStream_t stream) {
    const float* x  = (const float*)d_in[0];
    const float* Wq = (const float*)d_in[1];
    const float* bq = (const float*)d_in[2];
    const float* Wk = (const float*)d_in[3];
    const float* bk = (const float*)d_in[4];
    const float* Wv = (const float*)d_in[5];
    const float* bv = (const float*)d_in[6];
    float* out = (float*)d_out;

    float* ws = (float*)d_ws;
    float* Qw = ws;                       // [B][N][CQ]
    float* Kw = ws + 1048576;             // [B][CQ][N]
    float* Vw = ws + 2097152;             // [B][C][N]   (needs 16 MB of ws)

    dim3 gproj(Nn / 64, 4, Bn);
    qkv_proj<<<gproj, 256, 0, stream>>>(x, Wq, bq, Wk, bk, Wv, bv, Qw, Kw, Vw);

    dim3 gattn(Nn / 64, Bn);
    attn<<<gattn, 256, 0, stream>>>(Qw, Kw, Vw, out);
}

// Round 3
// 181.953 us; speedup vs baseline: 2.7615x; 2.7615x over previous
//
#include <hip/hip_runtime.h>

// Problem constants
#define Bn  4
#define Cn  128
#define CQn 64
#define Nn  4096

typedef _Float16 h8_t __attribute__((ext_vector_type(8)));
typedef float    f32x4 __attribute__((ext_vector_type(4)));
typedef unsigned int u32;
typedef u32      u32x2 __attribute__((ext_vector_type(2)));

// ws layout (halves):
//  Qh: [B][N][64]   offset 0        (1,048,576)
//  Kh: [B][N][64]   offset 1048576  (1,048,576)
//  Vt: [B][128][N]  offset 2097152  (2,097,152)   (V transposed: [C][N])

// ---------------------------------------------------------------------------
// Kernel 1: fused QKV projection (fp32 compute, f16 outputs in attn layouts)
// ---------------------------------------------------------------------------
__global__ __launch_bounds__(256) void qkv_proj(
    const float* __restrict__ x,
    const float* __restrict__ Wq, const float* __restrict__ bq,
    const float* __restrict__ Wk, const float* __restrict__ bk,
    const float* __restrict__ Wv, const float* __restrict__ bv,
    _Float16* __restrict__ Qh, _Float16* __restrict__ Kh, _Float16* __restrict__ Vt)
{
    const int ntile = blockIdx.x;
    const int otile = blockIdx.y;
    const int b     = blockIdx.z;
    const int tid   = threadIdx.x;
    const int nbase = ntile * 64;

    __shared__ float Ws[64][132];
    __shared__ float Xs[128][68];

    const float* Wsrc; const float* bsrc; int obase;
    if (otile == 0)      { Wsrc = Wq;                     bsrc = bq;      obase = 0; }
    else if (otile == 1) { Wsrc = Wk;                     bsrc = bk;      obase = 0; }
    else                 { Wsrc = Wv + (otile - 2) * 64 * Cn;
                           bsrc = bv + (otile - 2) * 64;  obase = (otile - 2) * 64; }

    for (int u = 0; u < 8; ++u) {
        int f = tid + u * 256;
        int row = f >> 5;
        int col = (f & 31) * 4;
        *(float4*)&Ws[row][col] = *(const float4*)&Wsrc[row * Cn + col];
    }
    const float* xb = x + ((size_t)b * Cn) * Nn + nbase;
    for (int u = 0; u < 8; ++u) {
        int f = tid + u * 256;
        int c = f >> 4;
        int n = (f & 15) * 4;
        *(float4*)&Xs[c][n] = *(const float4*)&xb[(size_t)c * Nn + n];
    }
    __syncthreads();

    const int o0 = (tid >> 4) * 4;
    const int n0 = (tid & 15) * 4;
    float acc[4][4] = {};

    for (int c = 0; c < Cn; c += 4) {
        float4 w4[4], x4[4];
        for (int oo = 0; oo < 4; ++oo) w4[oo] = *(const float4*)&Ws[o0 + oo][c];
        for (int cc = 0; cc < 4; ++cc) x4[cc] = *(const float4*)&Xs[c + cc][n0];
        for (int oo = 0; oo < 4; ++oo) {
            const float* wv = (const float*)&w4[oo];
            for (int cc = 0; cc < 4; ++cc) {
                const float wsv = wv[cc];
                const float* xp = (const float*)&x4[cc];
                acc[oo][0] += wsv * xp[0];
                acc[oo][1] += wsv * xp[1];
                acc[oo][2] += wsv * xp[2];
                acc[oo][3] += wsv * xp[3];
            }
        }
    }

    float bias[4];
    for (int oo = 0; oo < 4; ++oo) bias[oo] = bsrc[o0 + oo];

    union H4 { _Float16 e[4]; short4 v; };

    if (otile <= 1) {
        // Q/K layout [B][N][64], contiguous over channel
        _Float16* dst = (otile == 0 ? Qh : Kh) + ((size_t)b * Nn + nbase) * CQn;
        for (int nn = 0; nn < 4; ++nn) {
            H4 h;
            for (int oo = 0; oo < 4; ++oo) h.e[oo] = (_Float16)(acc[oo][nn] + bias[oo]);
            *(short4*)&dst[(size_t)(n0 + nn) * CQn + o0] = h.v;
        }
    } else {
        // V^T layout [B][C][N], contiguous over n
        _Float16* dst = Vt + (size_t)b * Cn * Nn;
        const int og = obase + o0;
        for (int oo = 0; oo < 4; ++oo) {
            H4 h;
            for (int nn = 0; nn < 4; ++nn) h.e[nn] = (_Float16)(acc[oo][nn] + bias[oo]);
            *(short4*)&dst[(size_t)(og + oo) * Nn + nbase + n0] = h.v;
        }
    }
}

// ---------------------------------------------------------------------------
// Kernel 2: MFMA flash attention.
// 4 waves/block; wave w owns 16 queries (cols). Swapped QK^T: D = S^T with
// col = query = lane&15, row = key-subrow 4g+r (HW-verified D layout).
// PV correctness-by-construction: P placed into A-slots by
//   kappa(e,g) = 4g + (e&3) + 16*(e>>2)   (+32 per second fragment)
// and V gathered into B-slots from LDS V^T tile by the SAME kappa, so the
// contraction pairs P[q][j] with V[c][j] for any true HW k-slot map.
// ---------------------------------------------------------------------------
__device__ __forceinline__ h8_t mkb(u32x2 lo, u32x2 hi) {
    union { h8_t h; u32 u[4]; } t;
    t.u[0] = lo[0]; t.u[1] = lo[1]; t.u[2] = hi[0]; t.u[3] = hi[1];
    return t.h;
}

__global__ __launch_bounds__(256) void attn_mfma(
    const _Float16* __restrict__ Qh, const _Float16* __restrict__ Kh,
    const _Float16* __restrict__ Vt, float* __restrict__ out)
{
    const int tid  = threadIdx.x;
    const int w    = tid >> 6;
    const int lane = tid & 63;
    const int g    = lane >> 4;
    const int ln   = lane & 15;
    const int b    = blockIdx.y;
    const int wib  = blockIdx.x * 64 + w * 16;

    __shared__ _Float16 Vs[128][68];   // [c][j], 136B stride

    // Persistent Q fragments (B operand: col=ln -> query wib+ln)
    const _Float16* qrow = Qh + ((size_t)(b * Nn + wib + ln)) * CQn + 8 * g;
    const h8_t q0 = *(const h8_t*)(qrow);
    const h8_t q1 = *(const h8_t*)(qrow + 32);

    const _Float16* Kb  = Kh + (size_t)b * Nn * CQn;
    const _Float16* Vtb = Vt + (size_t)b * Cn * Nn;

    f32x4 oacc[8];
    #pragma unroll
    for (int i = 0; i < 8; ++i) oacc[i] = (f32x4){0.f, 0.f, 0.f, 0.f};
    float m_run = -3.0e38f, l_run = 0.f;

    h8_t kfA[4][2], kfB[4][2];

    auto loadK = [&](h8_t (&kf)[4][2], int jt) {
        const _Float16* kbase = Kb + ((size_t)(jt * 64 + ln)) * CQn + 8 * g;
        #pragma unroll
        for (int js = 0; js < 4; ++js) {
            kf[js][0] = *(const h8_t*)(kbase + js * 16 * CQn);
            kf[js][1] = *(const h8_t*)(kbase + js * 16 * CQn + 32);
        }
    };

    auto tile = [&](h8_t (&kfU)[4][2], h8_t (&kfN)[4][2], int jt) {
        const int jbase = jt * 64;

        // 1) issue V-stage global loads early (latency hides under scores)
        float4 vr[4];
        const _Float16* vg = Vtb + jbase;
        #pragma unroll
        for (int u = 0; u < 4; ++u) {
            int f = tid + u * 256;
            vr[u] = *(const float4*)(vg + (size_t)(f >> 3) * Nn + (f & 7) * 8);
        }

        // 2) prefetch next K tile into registers
        loadK(kfN, (jt + 1) & 63);

        // 3) scores: st[js] rows = keys js*16+4g+r, col = query ln
        f32x4 st[4];
        #pragma unroll
        for (int js = 0; js < 4; ++js) {
            st[js] = (f32x4){0.f, 0.f, 0.f, 0.f};
            st[js] = __builtin_amdgcn_mfma_f32_16x16x32_f16(kfU[js][0], q0, st[js], 0, 0, 0);
            st[js] = __builtin_amdgcn_mfma_f32_16x16x32_f16(kfU[js][1], q1, st[js], 0, 0, 0);
        }

        // 4) online softmax (per query = per ln, replicated over g)
        float tmax = st[0][0];
        #pragma unroll
        for (int js = 0; js < 4; ++js)
            #pragma unroll
            for (int r = 0; r < 4; ++r) tmax = fmaxf(tmax, st[js][r]);
        tmax = fmaxf(tmax, __shfl_xor(tmax, 16));
        tmax = fmaxf(tmax, __shfl_xor(tmax, 32));
        const float mnew = fmaxf(m_run, tmax);
        float ts = 0.f;
        #pragma unroll
        for (int js = 0; js < 4; ++js)
            #pragma unroll
            for (int r = 0; r < 4; ++r) {
                float p = __expf(st[js][r] - mnew);
                st[js][r] = p;
                ts += p;
            }
        ts += __shfl_xor(ts, 16);
        ts += __shfl_xor(ts, 32);
        const float alpha = __expf(m_run - mnew);
        l_run = l_run * alpha + ts;
        m_run = mnew;

        // rescale oacc: D row r corresponds to query 4g+r -> fetch that
        // query's alpha from lane (0, 4g+r)
        const float a0 = __shfl(alpha, 4 * g + 0);
        const float a1 = __shfl(alpha, 4 * g + 1);
        const float a2 = __shfl(alpha, 4 * g + 2);
        const float a3 = __shfl(alpha, 4 * g + 3);
        #pragma unroll
        for (int cs = 0; cs < 8; ++cs) {
            oacc[cs][0] *= a0; oacc[cs][1] *= a1;
            oacc[cs][2] *= a2; oacc[cs][3] *= a3;
        }

        // P fragments: slot e of pa0 <- st[e>>2][e&3]  (j = kappa(e,g))
        //              slot e of pa1 <- st[2+(e>>2)][e&3] (j = 32+kappa(e,g))
        union H8 { h8_t h; _Float16 e[8]; };
        H8 p0u, p1u;
        #pragma unroll
        for (int r = 0; r < 4; ++r) {
            p0u.e[r]     = (_Float16)st[0][r];
            p0u.e[4 + r] = (_Float16)st[1][r];
            p1u.e[r]     = (_Float16)st[2][r];
            p1u.e[4 + r] = (_Float16)st[3][r];
        }
        const h8_t pa0 = p0u.h;
        const h8_t pa1 = p1u.h;

        // 5) stage V tile into LDS
        __syncthreads();
        #pragma unroll
        for (int u = 0; u < 4; ++u) {
            int f = tid + u * 256;
            *(float4*)&Vs[f >> 3][(f & 7) * 8] = vr[u];
        }
        __syncthreads();

        // 6) PV: per c-subtile, gather B-fragments by the same kappa map
        #pragma unroll
        for (int cs = 0; cs < 8; ++cs) {
            const _Float16* vrow = &Vs[cs * 16 + ln][0];
            u32x2 a0v = *(const u32x2*)(vrow + 4 * g);
            u32x2 a1v = *(const u32x2*)(vrow + 4 * g + 16);
            u32x2 b0v = *(const u32x2*)(vrow + 4 * g + 32);
            u32x2 b1v = *(const u32x2*)(vrow + 4 * g + 48);
            oacc[cs] = __builtin_amdgcn_mfma_f32_16x16x32_f16(pa0, mkb(a0v, a1v), oacc[cs], 0, 0, 0);
            oacc[cs] = __builtin_amdgcn_mfma_f32_16x16x32_f16(pa1, mkb(b0v, b1v), oacc[cs], 0, 0, 0);
        }
    };

    loadK(kfA, 0);
    for (int jt = 0; jt < 64; jt += 2) {
        tile(kfA, kfB, jt);
        tile(kfB, kfA, jt + 1);
    }

    // Epilogue: out[b][c][i], rows i = wib+4g+r, col c = cs*16+ln
    const float lr = 1.f / l_run;
    const float l0 = __shfl(lr, 4 * g + 0);
    const float l1 = __shfl(lr, 4 * g + 1);
    const float l2 = __shfl(lr, 4 * g + 2);
    const float l3 = __shfl(lr, 4 * g + 3);
    float* ob = out + (size_t)b * Cn * Nn;
    #pragma unroll
    for (int cs = 0; cs < 8; ++cs) {
        float4 o;
        o.x = oacc[cs][0] * l0;
        o.y = oacc[cs][1] * l1;
        o.z = oacc[cs][2] * l2;
        o.w = oacc[cs][3] * l3;
        *(float4*)&ob[(size_t)(cs * 16 + ln) * Nn + wib + 4 * g] = o;
    }
}

extern "C" void kernel_launch(void* const* d_in, const int* in_sizes, int n_in,
                              void* d_out, int out_size, void* d_ws, size_t ws_size,
                              hipStream_t stream) {
    const float* x  = (const float*)d_in[0];
    const float* Wq = (const float*)d_in[1];
    const float* bq = (const float*)d_in[2];
    const float* Wk = (const float*)d_in[3];
    const float* bk = (const float*)d_in[4];
    const float* Wv = (const float*)d_in[5];
    const float* bv = (const float*)d_in[6];
    float* out = (float*)d_out;

    _Float16* ws = (_Float16*)d_ws;
    _Float16* Qh = ws;
    _Float16* Kh = ws + 1048576;
    _Float16* Vt = ws + 2097152;

    dim3 gproj(Nn / 64, 4, Bn);
    qkv_proj<<<gproj, 256, 0, stream>>>(x, Wq, bq, Wk, bk, Wv, bv, Qh, Kh, Vt);

    dim3 gattn(Nn / 64, Bn);
    attn_mfma<<<gattn, 256, 0, stream>>>(Qh, Kh, Vt, out);
}